// Round 3
// baseline (165.668 us; speedup 1.0000x reference)
//
#include <hip/hip_runtime.h>
#include <hip/hip_cooperative_groups.h>

namespace cg = cooperative_groups;

#define BB 8
#define TT 24
#define NN 4096   // C*C
#define HH 32

struct Params {
    const float *Flow, *Edge, *W0, *b0, *W1, *b1, *W2, *b2;
    float *out, *xn, *s, *u;   // u: 3*BB*TT*HH accumulators
};

__device__ __forceinline__ void u_partials(const float (&xns)[TT][128],
                                           const float (&zs)[128][33],
                                           float* __restrict__ u, int tid) {
#pragma unroll
    for (int k = 0; k < 3; ++k) {
        int pidx = tid + k * 256;
        int t = pidx >> 5, h = pidx & 31;
        float acc = 0.f;
#pragma unroll 8
        for (int rr = 0; rr < 128; ++rr) acc += xns[t][rr] * zs[rr][h];
        atomicAdd(&u[t * HH + h], acc);
    }
}

__global__ __launch_bounds__(256, 1) void k_mega(Params p) {
    cg::grid_group grid = cg::this_grid();
    const int tid = threadIdx.x;
    const int blk = blockIdx.x;

    __shared__ float xns[TT][128];   // persistent xn tile (12 KB)
    __shared__ float xs[128][33];    // feature tile
    __shared__ float zs[128][33];    // persistent z tile
    __shared__ float Ws[32][32];
    __shared__ float us[TT][32];
    __shared__ float ss[TT];
    __shared__ float bs[32];
    __shared__ float rss[4], rsm[4];

    // ---------------- P0: row-normalize Flow rows; s; zero u ----------------
    if (blk < BB * TT) {
        const float* x = p.Flow + (size_t)blk * NN;
        float* xo = p.xn + (size_t)blk * NN;
        float4 v[4];
        float sq = 0.f, sm = 0.f;
#pragma unroll
        for (int i = 0; i < 4; ++i) {
            v[i] = ((const float4*)x)[tid + i * 256];
            sq += v[i].x * v[i].x + v[i].y * v[i].y + v[i].z * v[i].z + v[i].w * v[i].w;
            sm += v[i].x + v[i].y + v[i].z + v[i].w;
        }
#pragma unroll
        for (int off = 32; off > 0; off >>= 1) {
            sq += __shfl_down(sq, off);
            sm += __shfl_down(sm, off);
        }
        int wave = tid >> 6, lane = tid & 63;
        if (lane == 0) { rss[wave] = sq; rsm[wave] = sm; }
        __syncthreads();
        float tss = rss[0] + rss[1] + rss[2] + rss[3];
        float tsm = rsm[0] + rsm[1] + rsm[2] + rsm[3];
        float rn = 1.0f / fmaxf(sqrtf(tss), 1e-12f);
#pragma unroll
        for (int i = 0; i < 4; ++i) {
            v[i].x *= rn; v[i].y *= rn; v[i].z *= rn; v[i].w *= rn;
            ((float4*)xo)[tid + i * 256] = v[i];
        }
        if (tid == 0) p.s[blk] = tsm * rn;
    } else {
        for (int g = (blk - BB * TT) * 256 + tid; g < 3 * BB * TT * HH; g += 64 * 256)
            p.u[g] = 0.f;
    }
    grid.sync();

    const int b = blk >> 5;
    const int j0 = (blk & 31) * 128;
    const int r = tid >> 1;
    const int h0 = (tid & 1) * 16;
    float* u0 = p.u + b * TT * HH;
    float* u1 = u0 + BB * TT * HH;
    float* u2 = u1 + BB * TT * HH;

    // ---------------- P1: dinv (registers) + layer0 A ----------------
    if (tid < TT) ss[tid] = p.s[b * TT + tid];
    for (int i = tid; i < 1024; i += 256) Ws[i >> 5][i & 31] = p.W0[i];
    const float* eb = p.Edge + ((size_t)b * NN + j0) * HH;
    for (int i = tid; i < 4096; i += 256) xs[i >> 5][i & 31] = eb[i];
    const float* xnb = p.xn + (size_t)b * TT * NN + j0;
    for (int i = tid; i < TT * 128; i += 256) xns[i >> 7][i & 127] = xnb[(i >> 7) * NN + (i & 127)];
    __syncthreads();

    float deg = 1.0f;
#pragma unroll
    for (int t = 0; t < TT; ++t) deg += xns[t][r] * ss[t];
    const float di = (deg > 0.f) ? rsqrtf(deg) : 0.f;

#pragma unroll
    for (int hh = 0; hh < 16; ++hh) {
        float acc = 0.f;
#pragma unroll
        for (int e = 0; e < 32; ++e) acc += xs[r][e] * Ws[e][h0 + hh];
        zs[r][h0 + hh] = di * acc;
    }
    __syncthreads();
    u_partials(xns, zs, u0, tid);
    grid.sync();

    // ---------------- P2/P3: fused B(l) + A(l+1) ----------------
    const float* Warr[2] = { p.W1, p.W2 };
    const float* barr[2] = { p.b0, p.b1 };
    float* uin[2] = { u0, u1 };
    float* uout[2] = { u1, u2 };
#pragma unroll
    for (int l = 0; l < 2; ++l) {
        for (int i = tid; i < TT * HH; i += 256) us[i >> 5][i & 31] = uin[l][i];
        if (tid < 32) bs[tid] = barr[l][tid];
        for (int i = tid; i < 1024; i += 256) Ws[i >> 5][i & 31] = Warr[l][i];
        __syncthreads();
        // B-phase: next-layer input rows -> xs
        float zreg[16];
#pragma unroll
        for (int hh = 0; hh < 16; ++hh) zreg[hh] = zs[r][h0 + hh];
#pragma unroll
        for (int hh = 0; hh < 16; ++hh) {
            int h = h0 + hh;
            float acc = 0.f;
#pragma unroll
            for (int t = 0; t < TT; ++t) acc += xns[t][r] * us[t][h];
            xs[r][h] = fmaxf(di * (acc + zreg[hh]) + bs[h], 0.f);
        }
        // A-phase (pair lane tid^1 wrote other half of xs[r]; same wave64 ->
        // program-order LDS visibility, validated in R1's fused kernel)
#pragma unroll
        for (int hh = 0; hh < 16; ++hh) {
            float acc = 0.f;
#pragma unroll
            for (int e = 0; e < 32; ++e) acc += xs[r][e] * Ws[e][h0 + hh];
            zs[r][h0 + hh] = di * acc;
        }
        __syncthreads();
        u_partials(xns, zs, uout[l], tid);
        grid.sync();
    }

    // ---------------- P4: final B -> out ----------------
    for (int i = tid; i < TT * HH; i += 256) us[i >> 5][i & 31] = u2[i];
    if (tid < 32) bs[tid] = p.b2[tid];
    __syncthreads();
    float o[16];
#pragma unroll
    for (int hh = 0; hh < 16; ++hh) {
        int h = h0 + hh;
        float acc = 0.f;
#pragma unroll
        for (int t = 0; t < TT; ++t) acc += xns[t][r] * us[t][h];
        o[hh] = fmaxf(di * (acc + zs[r][h]) + bs[h], 0.f);
    }
    float* orow = p.out + ((size_t)b * NN + j0 + r) * HH + h0;
#pragma unroll
    for (int q = 0; q < 4; ++q)
        ((float4*)orow)[q] = make_float4(o[4 * q], o[4 * q + 1], o[4 * q + 2], o[4 * q + 3]);
}

// ======================= fallback path (R1, 5 launches) =======================
__global__ __launch_bounds__(256) void k_norm(const float* __restrict__ Flow,
                                              float* __restrict__ xn,
                                              float* __restrict__ s,
                                              float* __restrict__ u) {
    int row = blockIdx.x;
    int tid = threadIdx.x;
    const float* x = Flow + (size_t)row * NN;
    float* xo = xn + (size_t)row * NN;
    float4 v[4];
    float ssq = 0.f, sm = 0.f;
#pragma unroll
    for (int i = 0; i < 4; ++i) {
        v[i] = ((const float4*)x)[tid + i * 256];
        ssq += v[i].x * v[i].x + v[i].y * v[i].y + v[i].z * v[i].z + v[i].w * v[i].w;
        sm += v[i].x + v[i].y + v[i].z + v[i].w;
    }
#pragma unroll
    for (int off = 32; off > 0; off >>= 1) {
        ssq += __shfl_down(ssq, off);
        sm += __shfl_down(sm, off);
    }
    __shared__ float rss[4], rsm[4];
    int wave = tid >> 6, lane = tid & 63;
    if (lane == 0) { rss[wave] = ssq; rsm[wave] = sm; }
    __syncthreads();
    float tss = rss[0] + rss[1] + rss[2] + rss[3];
    float tsm = rsm[0] + rsm[1] + rsm[2] + rsm[3];
    float rn = 1.0f / fmaxf(sqrtf(tss), 1e-12f);
#pragma unroll
    for (int i = 0; i < 4; ++i) {
        v[i].x *= rn; v[i].y *= rn; v[i].z *= rn; v[i].w *= rn;
        ((float4*)xo)[tid + i * 256] = v[i];
    }
    if (tid == 0) s[row] = tsm * rn;
    int gid = row * 256 + tid;
    if (gid < 3 * BB * TT * HH) u[gid] = 0.f;
}

__global__ __launch_bounds__(256) void k_dinvA(const float* __restrict__ Edge,
                                               const float* __restrict__ W,
                                               const float* __restrict__ xn,
                                               const float* __restrict__ s,
                                               float* __restrict__ dinv,
                                               float* __restrict__ z,
                                               float* __restrict__ u) {
    int b = blockIdx.y;
    int j0 = blockIdx.x * 128;
    int tid = threadIdx.x;
    __shared__ float Ws[32][32];
    __shared__ float xs[128][33];
    __shared__ float zs[128][33];
    __shared__ float xns[TT][128];
    __shared__ float ss[TT];
    if (tid < TT) ss[tid] = s[b * TT + tid];
    for (int i = tid; i < 1024; i += 256) Ws[i >> 5][i & 31] = W[i];
    const float* xb = Edge + ((size_t)b * NN + j0) * HH;
    for (int i = tid; i < 4096; i += 256) xs[i >> 5][i & 31] = xb[i];
    const float* xnb = xn + (size_t)b * TT * NN + j0;
    for (int i = tid; i < TT * 128; i += 256) xns[i >> 7][i & 127] = xnb[(i >> 7) * NN + (i & 127)];
    __syncthreads();
    int r = tid >> 1;
    int h0 = (tid & 1) * 16;
    float deg = 1.0f;
#pragma unroll
    for (int t = 0; t < TT; ++t) deg += xns[t][r] * ss[t];
    float di = (deg > 0.f) ? rsqrtf(deg) : 0.f;
    if ((tid & 1) == 0) dinv[b * NN + j0 + r] = di;
    float zr[16];
#pragma unroll
    for (int hh = 0; hh < 16; ++hh) {
        float acc = 0.f;
#pragma unroll
        for (int e = 0; e < 32; ++e) acc += xs[r][e] * Ws[e][h0 + hh];
        zr[hh] = di * acc;
        zs[r][h0 + hh] = zr[hh];
    }
    float* zb = z + ((size_t)b * NN + j0 + r) * HH + h0;
#pragma unroll
    for (int q = 0; q < 4; ++q)
        ((float4*)zb)[q] = make_float4(zr[4 * q], zr[4 * q + 1], zr[4 * q + 2], zr[4 * q + 3]);
    __syncthreads();
    u_partials(xns, zs, u + b * TT * HH, tid);
}

__global__ __launch_bounds__(256) void k_fusedBA(const float* __restrict__ z_in,
                                                 const float* __restrict__ xn,
                                                 const float* __restrict__ u_in,
                                                 const float* __restrict__ dinv,
                                                 const float* __restrict__ bias,
                                                 const float* __restrict__ W,
                                                 float* __restrict__ z_out,
                                                 float* __restrict__ u_out) {
    int b = blockIdx.y;
    int j0 = blockIdx.x * 128;
    int tid = threadIdx.x;
    __shared__ float us[TT][32];
    __shared__ float xns[TT][128];
    __shared__ float Ws[32][32];
    __shared__ float xs[128][33];
    __shared__ float zs[128][33];
    __shared__ float bs[32];
    for (int i = tid; i < TT * HH; i += 256) us[i >> 5][i & 31] = u_in[b * TT * HH + i];
    if (tid < 32) bs[tid] = bias[tid];
    for (int i = tid; i < 1024; i += 256) Ws[i >> 5][i & 31] = W[i];
    const float* xnb = xn + (size_t)b * TT * NN + j0;
    for (int i = tid; i < TT * 128; i += 256) xns[i >> 7][i & 127] = xnb[(i >> 7) * NN + (i & 127)];
    __syncthreads();
    int r = tid >> 1;
    int h0 = (tid & 1) * 16;
    float di = dinv[b * NN + j0 + r];
    const float* zrow = z_in + ((size_t)b * NN + j0 + r) * HH + h0;
    float4 zv[4];
#pragma unroll
    for (int q = 0; q < 4; ++q) zv[q] = ((const float4*)zrow)[q];
    float zreg[16];
#pragma unroll
    for (int q = 0; q < 4; ++q) {
        zreg[4 * q] = zv[q].x; zreg[4 * q + 1] = zv[q].y;
        zreg[4 * q + 2] = zv[q].z; zreg[4 * q + 3] = zv[q].w;
    }
#pragma unroll
    for (int hh = 0; hh < 16; ++hh) {
        int h = h0 + hh;
        float acc = 0.f;
#pragma unroll
        for (int t = 0; t < TT; ++t) acc += xns[t][r] * us[t][h];
        xs[r][h] = fmaxf(di * (acc + zreg[hh]) + bs[h], 0.f);
    }
    float zr[16];
#pragma unroll
    for (int hh = 0; hh < 16; ++hh) {
        float acc = 0.f;
#pragma unroll
        for (int e = 0; e < 32; ++e) acc += xs[r][e] * Ws[e][h0 + hh];
        zr[hh] = di * acc;
        zs[r][h0 + hh] = zr[hh];
    }
    float* zb = z_out + ((size_t)b * NN + j0 + r) * HH + h0;
#pragma unroll
    for (int q = 0; q < 4; ++q)
        ((float4*)zb)[q] = make_float4(zr[4 * q], zr[4 * q + 1], zr[4 * q + 2], zr[4 * q + 3]);
    __syncthreads();
    u_partials(xns, zs, u_out + b * TT * HH, tid);
}

__global__ __launch_bounds__(256) void k_layerB(const float* __restrict__ z,
                                                const float* __restrict__ xn,
                                                const float* __restrict__ u,
                                                const float* __restrict__ dinv,
                                                const float* __restrict__ bias,
                                                float* __restrict__ out) {
    int b = blockIdx.y;
    int j0 = blockIdx.x * 128;
    int tid = threadIdx.x;
    __shared__ float us[TT][32];
    __shared__ float xns[TT][128];
    __shared__ float bs[32];
    for (int i = tid; i < TT * HH; i += 256) us[i >> 5][i & 31] = u[b * TT * HH + i];
    if (tid < 32) bs[tid] = bias[tid];
    const float* xnb = xn + (size_t)b * TT * NN + j0;
    for (int i = tid; i < TT * 128; i += 256) xns[i >> 7][i & 127] = xnb[(i >> 7) * NN + (i & 127)];
    __syncthreads();
    int r = tid >> 1;
    int h0 = (tid & 1) * 16;
    float di = dinv[b * NN + j0 + r];
    const float* zrow = z + ((size_t)b * NN + j0 + r) * HH + h0;
    float* orow = out + ((size_t)b * NN + j0 + r) * HH + h0;
    float4 zv[4];
#pragma unroll
    for (int q = 0; q < 4; ++q) zv[q] = ((const float4*)zrow)[q];
    float zreg[16];
#pragma unroll
    for (int q = 0; q < 4; ++q) {
        zreg[4 * q] = zv[q].x; zreg[4 * q + 1] = zv[q].y;
        zreg[4 * q + 2] = zv[q].z; zreg[4 * q + 3] = zv[q].w;
    }
    float o[16];
#pragma unroll
    for (int hh = 0; hh < 16; ++hh) {
        int h = h0 + hh;
        float acc = 0.f;
#pragma unroll
        for (int t = 0; t < TT; ++t) acc += xns[t][r] * us[t][h];
        o[hh] = fmaxf(di * (acc + zreg[hh]) + bs[h], 0.f);
    }
#pragma unroll
    for (int q = 0; q < 4; ++q)
        ((float4*)orow)[q] = make_float4(o[4 * q], o[4 * q + 1], o[4 * q + 2], o[4 * q + 3]);
}

extern "C" void kernel_launch(void* const* d_in, const int* in_sizes, int n_in,
                              void* d_out, int out_size, void* d_ws, size_t ws_size,
                              hipStream_t stream) {
    const float* Flow = (const float*)d_in[0];
    const float* Edge = (const float*)d_in[1];
    const float* W0 = (const float*)d_in[2];
    const float* b0 = (const float*)d_in[3];
    const float* W1 = (const float*)d_in[4];
    const float* b1 = (const float*)d_in[5];
    const float* W2 = (const float*)d_in[6];
    const float* b2 = (const float*)d_in[7];
    float* out = (float*)d_out;

    float* ws = (float*)d_ws;
    float* xn   = ws;                                  // B*T*N
    float* s    = xn + (size_t)BB * TT * NN;           // B*T
    float* dinv = s + BB * TT;                         // B*N (fallback only)
    float* zA   = dinv + (size_t)BB * NN;              // B*N*H (fallback only)
    float* zB   = zA + (size_t)BB * NN * HH;           // B*N*H (fallback only)
    float* u    = zB + (size_t)BB * NN * HH;           // 3*B*T*H

    Params p = { Flow, Edge, W0, b0, W1, b1, W2, b2, out, xn, s, u };
    void* args[] = { &p };
    hipError_t rc = hipLaunchCooperativeKernel(k_mega, dim3(256), dim3(256),
                                               args, 0, stream);
    if (rc != hipSuccess) {
        float* u0 = u, *u1 = u + BB * TT * HH, *u2 = u + 2 * BB * TT * HH;
        k_norm<<<dim3(BB * TT), 256, 0, stream>>>(Flow, xn, s, u);
        k_dinvA<<<dim3(32, BB), 256, 0, stream>>>(Edge, W0, xn, s, dinv, zA, u0);
        k_fusedBA<<<dim3(32, BB), 256, 0, stream>>>(zA, xn, u0, dinv, b0, W1, zB, u1);
        k_fusedBA<<<dim3(32, BB), 256, 0, stream>>>(zB, xn, u1, dinv, b1, W2, zA, u2);
        k_layerB<<<dim3(32, BB), 256, 0, stream>>>(zA, xn, u2, dinv, b2, out);
    }
}

// Round 4
// 75.413 us; speedup vs baseline: 2.1968x; 2.1968x over previous
//
#include <hip/hip_runtime.h>

#define BB 8
#define TT 24
#define NN 4096   // C*C
#define HH 32
#define NCHUNK 32 // j-tiles per batch
#define UP 768    // TT*HH partial size

// ---------------- K1: fused row-norm + dinv + layer0-A ----------------
// Each block (b, chunk) redundantly computes its batch's 24 row norms (L2-hot),
// builds its xn tile, computes dinv (registers), z0 = dinv.*(Edge@W0), and the
// u0 partial for its tile. Removes the separate norm kernel + its launch gap.
__global__ __launch_bounds__(256) void k_normA0(const float* __restrict__ Flow,
                                                const float* __restrict__ Edge,
                                                const float* __restrict__ W0,
                                                float* __restrict__ xn,
                                                float* __restrict__ dinv,
                                                float* __restrict__ z0,
                                                float* __restrict__ u0p) {
    const int blk = blockIdx.x;
    const int b = blk >> 5;
    const int chunk = blk & 31;
    const int j0 = chunk * 128;
    const int tid = threadIdx.x;

    __shared__ float xns[TT][128];
    __shared__ float xs[128][33];
    __shared__ float zs[128][33];
    __shared__ float Ws[32][32];
    __shared__ float ssA[TT], smA[TT], rnA[TT], sA[TT];

    // phase 1: full-row sq/sum reductions, wave w owns rows w*6..w*6+5
    {
        const int wave = tid >> 6, lane = tid & 63;
        const float4* fb = (const float4*)(Flow + (size_t)b * TT * NN);
#pragma unroll
        for (int q = 0; q < 6; ++q) {
            int t = wave * 6 + q;
            const float4* rowp = fb + t * (NN / 4);
            float sq = 0.f, sm = 0.f;
#pragma unroll
            for (int k = 0; k < 16; ++k) {
                float4 v = rowp[lane + 64 * k];
                sq += v.x * v.x + v.y * v.y + v.z * v.z + v.w * v.w;
                sm += v.x + v.y + v.z + v.w;
            }
#pragma unroll
            for (int off = 32; off > 0; off >>= 1) {
                sq += __shfl_down(sq, off);
                sm += __shfl_down(sm, off);
            }
            if (lane == 0) { ssA[t] = sq; smA[t] = sm; }
        }
    }
    __syncthreads();
    if (tid < TT) {
        float rn = 1.0f / fmaxf(sqrtf(ssA[tid]), 1e-12f);
        rnA[tid] = rn;
        sA[tid] = smA[tid] * rn;
    }
    // independent stages meanwhile
    for (int i = tid; i < 1024; i += 256) Ws[i >> 5][i & 31] = W0[i];
    const float* eb = Edge + ((size_t)b * NN + j0) * HH;
    for (int i = tid; i < 4096; i += 256) xs[i >> 5][i & 31] = eb[i];
    __syncthreads();

    // phase 2: xn tile = Flow tile * rn; also persist to global for K2..K4
    const float* flb = Flow + (size_t)b * TT * NN + j0;
    float* xnb = xn + (size_t)b * TT * NN + j0;
    for (int i = tid; i < TT * 128; i += 256) {
        int t = i >> 7, j = i & 127;
        float v = flb[t * NN + j] * rnA[t];
        xns[t][j] = v;
        xnb[t * NN + j] = v;
    }
    __syncthreads();

    // phase 3: dinv + z0 + u0 partial
    const int r = tid >> 1;
    const int h0 = (tid & 1) * 16;
    float deg = 1.0f;
#pragma unroll
    for (int t = 0; t < TT; ++t) deg += xns[t][r] * sA[t];
    const float di = (deg > 0.f) ? rsqrtf(deg) : 0.f;
    if ((tid & 1) == 0) dinv[b * NN + j0 + r] = di;

    float zr[16];
#pragma unroll
    for (int hh = 0; hh < 16; ++hh) {
        float acc = 0.f;
#pragma unroll
        for (int e = 0; e < 32; ++e) acc += xs[r][e] * Ws[e][h0 + hh];
        zr[hh] = di * acc;
        zs[r][h0 + hh] = zr[hh];
    }
    float* zb = z0 + ((size_t)b * NN + j0 + r) * HH + h0;
#pragma unroll
    for (int q = 0; q < 4; ++q)
        ((float4*)zb)[q] = make_float4(zr[4 * q], zr[4 * q + 1], zr[4 * q + 2], zr[4 * q + 3]);
    __syncthreads();

    float* up = u0p + (size_t)(b * NCHUNK + chunk) * UP;
#pragma unroll
    for (int k = 0; k < 3; ++k) {
        int p = tid + k * 256;
        int t = p >> 5, h = p & 31;
        float acc = 0.f;
#pragma unroll 8
        for (int rr = 0; rr < 128; ++rr) acc += xns[t][rr] * zs[rr][h];
        up[p] = acc;
    }
}

// ---------------- K2/K3: fused B(l)+A(l+1), partial-based u ----------------
__global__ __launch_bounds__(256) void k_BA(const float* __restrict__ z_in,
                                            const float* __restrict__ xn,
                                            const float* __restrict__ u_in_p,
                                            const float* __restrict__ dinv,
                                            const float* __restrict__ bias,
                                            const float* __restrict__ W,
                                            float* __restrict__ z_out,
                                            float* __restrict__ u_out_p) {
    const int blk = blockIdx.x;
    const int b = blk >> 5;
    const int chunk = blk & 31;
    const int j0 = chunk * 128;
    const int tid = threadIdx.x;

    __shared__ float us[TT][32];
    __shared__ float xns[TT][128];
    __shared__ float Ws[32][32];
    __shared__ float xs[128][33];
    __shared__ float zs[128][33];
    __shared__ float bs[32];

    if (tid < 32) bs[tid] = bias[tid];
    for (int i = tid; i < 1024; i += 256) Ws[i >> 5][i & 31] = W[i];
    const float* xnb = xn + (size_t)b * TT * NN + j0;
    for (int i = tid; i < TT * 128; i += 256) xns[i >> 7][i & 127] = xnb[(i >> 7) * NN + (i & 127)];
    // reduce u partials over the batch's 32 chunks (L2-hot)
    {
        const float* up = u_in_p + (size_t)b * NCHUNK * UP;
#pragma unroll
        for (int k = 0; k < 3; ++k) {
            int p = tid + k * 256;
            float acc = 0.f;
#pragma unroll 8
            for (int c = 0; c < NCHUNK; ++c) acc += up[c * UP + p];
            us[p >> 5][p & 31] = acc;
        }
    }
    const int r = tid >> 1;
    const int h0 = (tid & 1) * 16;
    const float di = dinv[b * NN + j0 + r];
    const float* zrow = z_in + ((size_t)b * NN + j0 + r) * HH + h0;
    float4 zv[4];
#pragma unroll
    for (int q = 0; q < 4; ++q) zv[q] = ((const float4*)zrow)[q];
    __syncthreads();

    float zreg[16];
#pragma unroll
    for (int q = 0; q < 4; ++q) {
        zreg[4 * q] = zv[q].x; zreg[4 * q + 1] = zv[q].y;
        zreg[4 * q + 2] = zv[q].z; zreg[4 * q + 3] = zv[q].w;
    }
    // B-phase: next-layer input row half -> xs
#pragma unroll
    for (int hh = 0; hh < 16; ++hh) {
        int h = h0 + hh;
        float acc = 0.f;
#pragma unroll
        for (int t = 0; t < TT; ++t) acc += xns[t][r] * us[t][h];
        xs[r][h] = fmaxf(di * (acc + zreg[hh]) + bs[h], 0.f);
    }
    // A-phase (pair lane tid^1 wrote the other half of xs[r]; same wave64 ->
    // program-order LDS visibility, validated R1/R2)
    float zr[16];
#pragma unroll
    for (int hh = 0; hh < 16; ++hh) {
        float acc = 0.f;
#pragma unroll
        for (int e = 0; e < 32; ++e) acc += xs[r][e] * Ws[e][h0 + hh];
        zr[hh] = di * acc;
        zs[r][h0 + hh] = zr[hh];
    }
    float* zb = z_out + ((size_t)b * NN + j0 + r) * HH + h0;
#pragma unroll
    for (int q = 0; q < 4; ++q)
        ((float4*)zb)[q] = make_float4(zr[4 * q], zr[4 * q + 1], zr[4 * q + 2], zr[4 * q + 3]);
    __syncthreads();

    float* up = u_out_p + (size_t)(b * NCHUNK + chunk) * UP;
#pragma unroll
    for (int k = 0; k < 3; ++k) {
        int p = tid + k * 256;
        int t = p >> 5, h = p & 31;
        float acc = 0.f;
#pragma unroll 8
        for (int rr = 0; rr < 128; ++rr) acc += xns[t][rr] * zs[rr][h];
        up[p] = acc;
    }
}

// ---------------- K4: final B -> out ----------------
__global__ __launch_bounds__(256) void k_Bfin(const float* __restrict__ z_in,
                                              const float* __restrict__ xn,
                                              const float* __restrict__ u_in_p,
                                              const float* __restrict__ dinv,
                                              const float* __restrict__ bias,
                                              float* __restrict__ out) {
    const int blk = blockIdx.x;
    const int b = blk >> 5;
    const int j0 = (blk & 31) * 128;
    const int tid = threadIdx.x;

    __shared__ float us[TT][32];
    __shared__ float xns[TT][128];
    __shared__ float bs[32];

    if (tid < 32) bs[tid] = bias[tid];
    const float* xnb = xn + (size_t)b * TT * NN + j0;
    for (int i = tid; i < TT * 128; i += 256) xns[i >> 7][i & 127] = xnb[(i >> 7) * NN + (i & 127)];
    {
        const float* up = u_in_p + (size_t)b * NCHUNK * UP;
#pragma unroll
        for (int k = 0; k < 3; ++k) {
            int p = tid + k * 256;
            float acc = 0.f;
#pragma unroll 8
            for (int c = 0; c < NCHUNK; ++c) acc += up[c * UP + p];
            us[p >> 5][p & 31] = acc;
        }
    }
    const int r = tid >> 1;
    const int h0 = (tid & 1) * 16;
    const float di = dinv[b * NN + j0 + r];
    const float* zrow = z_in + ((size_t)b * NN + j0 + r) * HH + h0;
    float4 zv[4];
#pragma unroll
    for (int q = 0; q < 4; ++q) zv[q] = ((const float4*)zrow)[q];
    __syncthreads();

    float zreg[16];
#pragma unroll
    for (int q = 0; q < 4; ++q) {
        zreg[4 * q] = zv[q].x; zreg[4 * q + 1] = zv[q].y;
        zreg[4 * q + 2] = zv[q].z; zreg[4 * q + 3] = zv[q].w;
    }
    float o[16];
#pragma unroll
    for (int hh = 0; hh < 16; ++hh) {
        int h = h0 + hh;
        float acc = 0.f;
#pragma unroll
        for (int t = 0; t < TT; ++t) acc += xns[t][r] * us[t][h];
        o[hh] = fmaxf(di * (acc + zreg[hh]) + bs[h], 0.f);
    }
    float* orow = out + ((size_t)b * NN + j0 + r) * HH + h0;
#pragma unroll
    for (int q = 0; q < 4; ++q)
        ((float4*)orow)[q] = make_float4(o[4 * q], o[4 * q + 1], o[4 * q + 2], o[4 * q + 3]);
}

extern "C" void kernel_launch(void* const* d_in, const int* in_sizes, int n_in,
                              void* d_out, int out_size, void* d_ws, size_t ws_size,
                              hipStream_t stream) {
    const float* Flow = (const float*)d_in[0];
    const float* Edge = (const float*)d_in[1];
    const float* W0 = (const float*)d_in[2];
    const float* b0 = (const float*)d_in[3];
    const float* W1 = (const float*)d_in[4];
    const float* b1 = (const float*)d_in[5];
    const float* W2 = (const float*)d_in[6];
    const float* b2 = (const float*)d_in[7];
    float* out = (float*)d_out;

    float* ws = (float*)d_ws;
    float* xn   = ws;                                   // B*T*N      (786432)
    float* dinv = xn + (size_t)BB * TT * NN;            // B*N        (32768)
    float* zA   = dinv + (size_t)BB * NN;               // B*N*H      (1048576)
    float* zB   = zA + (size_t)BB * NN * HH;            // B*N*H      (1048576)
    float* up0  = zB + (size_t)BB * NN * HH;            // B*32*768   (196608)
    float* up1  = up0 + (size_t)BB * NCHUNK * UP;
    float* up2  = up1 + (size_t)BB * NCHUNK * UP;

    k_normA0<<<dim3(256), 256, 0, stream>>>(Flow, Edge, W0, xn, dinv, zA, up0);
    k_BA<<<dim3(256), 256, 0, stream>>>(zA, xn, up0, dinv, b0, W1, zB, up1);
    k_BA<<<dim3(256), 256, 0, stream>>>(zB, xn, up1, dinv, b1, W2, zA, up2);
    k_Bfin<<<dim3(256), 256, 0, stream>>>(zA, xn, up2, dinv, b2, out);
}

// Round 5
// 46.342 us; speedup vs baseline: 3.5749x; 1.6273x over previous
//
#include <hip/hip_runtime.h>

#define BB 8
#define TT 24
#define NN 4096   // C*C
#define HH 32
#define JT 64     // j-tile width
#define UPB (TT*HH) // 768

// ---------------- K1: row norms only -> rn[row], s[row]; zero u ----------------
__global__ __launch_bounds__(256) void k_norm(const float* __restrict__ Flow,
                                              float* __restrict__ rn,
                                              float* __restrict__ s,
                                              float* __restrict__ u /*3*B*T*H*/) {
    int row = blockIdx.x;                 // 0..B*T-1
    int tid = threadIdx.x;
    const float4* x = (const float4*)(Flow + (size_t)row * NN);
    float sq = 0.f, sm = 0.f;
#pragma unroll
    for (int i = 0; i < 4; ++i) {
        float4 v = x[tid + i * 256];
        sq += v.x * v.x + v.y * v.y + v.z * v.z + v.w * v.w;
        sm += v.x + v.y + v.z + v.w;
    }
#pragma unroll
    for (int off = 32; off > 0; off >>= 1) {
        sq += __shfl_down(sq, off);
        sm += __shfl_down(sm, off);
    }
    __shared__ float rss[4], rsm[4];
    int wave = tid >> 6, lane = tid & 63;
    if (lane == 0) { rss[wave] = sq; rsm[wave] = sm; }
    __syncthreads();
    if (tid == 0) {
        float tss = rss[0] + rss[1] + rss[2] + rss[3];
        float tsm = rsm[0] + rsm[1] + rsm[2] + rsm[3];
        float r = 1.0f / fmaxf(sqrtf(tss), 1e-12f);
        rn[row] = r;
        s[row] = tsm * r;
    }
    int gid = row * 256 + tid;
    if (gid < 3 * BB * TT * HH) u[gid] = 0.f;
}

// ---------------- K2: dinv + layer0-A (tile = 64 cols, grid 512) ----------------
__global__ __launch_bounds__(256) void k_dinvA0(const float* __restrict__ Flow,
                                                const float* __restrict__ Edge,
                                                const float* __restrict__ W0,
                                                const float* __restrict__ rn,
                                                const float* __restrict__ s,
                                                float* __restrict__ dinv,
                                                float* __restrict__ z0,
                                                float* __restrict__ u0) {
    const int blk = blockIdx.x;
    const int b = blk >> 6;
    const int j0 = (blk & 63) * JT;
    const int tid = threadIdx.x;

    __shared__ float xns[TT][JT];     // xn tile
    __shared__ float xs[JT][33];      // Edge tile
    __shared__ float zs[JT][33];
    __shared__ float Ws[32][32];
    __shared__ float sS[TT];

    if (tid < TT) sS[tid] = s[b * TT + tid];
    for (int i = tid; i < 1024; i += 256) Ws[i >> 5][i & 31] = W0[i];
    // Edge tile: contiguous 64*32 floats
    {
        const float4* eb = (const float4*)(Edge + ((size_t)b * NN + j0) * HH);
#pragma unroll
        for (int k = 0; k < 2; ++k) {
            int i = tid + k * 256;
            float4 v = eb[i];
            int r0 = i >> 3, c0 = (i & 7) * 4;
            xs[r0][c0] = v.x; xs[r0][c0 + 1] = v.y; xs[r0][c0 + 2] = v.z; xs[r0][c0 + 3] = v.w;
        }
    }
    // xn tile = Flow tile * rn[t]  (384 float4)
    {
        const float* flb = Flow + (size_t)b * TT * NN + j0;
        for (int i = tid; i < TT * (JT / 4); i += 256) {
            int t = i >> 4, c0 = (i & 15) * 4;
            float4 v = ((const float4*)(flb + t * NN))[i & 15];
            float rt = rn[b * TT + t];
            xns[t][c0] = v.x * rt; xns[t][c0 + 1] = v.y * rt;
            xns[t][c0 + 2] = v.z * rt; xns[t][c0 + 3] = v.w * rt;
        }
    }
    __syncthreads();

    const int r = tid >> 2;           // 0..63
    const int h0 = (tid & 3) * 8;     // 0,8,16,24
    float deg = 1.0f;
#pragma unroll
    for (int t = 0; t < TT; ++t) deg += xns[t][r] * sS[t];
    const float di = (deg > 0.f) ? rsqrtf(deg) : 0.f;
    if ((tid & 3) == 0) dinv[b * NN + j0 + r] = di;

    float zr[8];
#pragma unroll
    for (int hh = 0; hh < 8; ++hh) {
        float acc = 0.f;
#pragma unroll
        for (int e = 0; e < 32; ++e) acc += xs[r][e] * Ws[e][h0 + hh];
        zr[hh] = di * acc;
        zs[r][h0 + hh] = zr[hh];
    }
    float* zb = z0 + ((size_t)b * NN + j0 + r) * HH + h0;
    ((float4*)zb)[0] = make_float4(zr[0], zr[1], zr[2], zr[3]);
    ((float4*)zb)[1] = make_float4(zr[4], zr[5], zr[6], zr[7]);
    __syncthreads();

#pragma unroll
    for (int k = 0; k < 3; ++k) {
        int p = tid + k * 256;
        int t = p >> 5, h = p & 31;
        float acc = 0.f;
#pragma unroll 8
        for (int rr = 0; rr < JT; ++rr) acc += xns[t][rr] * zs[rr][h];
        atomicAdd(&u0[(b * TT + t) * HH + h], acc);
    }
}

// ---------------- K3/K4: fused B(l)+A(l+1) ----------------
__global__ __launch_bounds__(256) void k_BA(const float* __restrict__ z_in,
                                            const float* __restrict__ Flow,
                                            const float* __restrict__ rn,
                                            const float* __restrict__ u_in,
                                            const float* __restrict__ dinv,
                                            const float* __restrict__ bias,
                                            const float* __restrict__ W,
                                            float* __restrict__ z_out,
                                            float* __restrict__ u_out) {
    const int blk = blockIdx.x;
    const int b = blk >> 6;
    const int j0 = (blk & 63) * JT;
    const int tid = threadIdx.x;

    __shared__ float us[TT][32];
    __shared__ float xns[TT][JT];
    __shared__ float Ws[32][32];
    __shared__ float xs[JT][33];
    __shared__ float zs[JT][33];
    __shared__ float bs[32];

    if (tid < 32) bs[tid] = bias[tid];
    for (int i = tid; i < 1024; i += 256) Ws[i >> 5][i & 31] = W[i];
    if (tid < UPB / 4) {
        float4 v = ((const float4*)(u_in + b * UPB))[tid];
        int t = tid >> 3, c0 = (tid & 7) * 4;
        us[t][c0] = v.x; us[t][c0 + 1] = v.y; us[t][c0 + 2] = v.z; us[t][c0 + 3] = v.w;
    }
    {
        const float* flb = Flow + (size_t)b * TT * NN + j0;
        for (int i = tid; i < TT * (JT / 4); i += 256) {
            int t = i >> 4, c0 = (i & 15) * 4;
            float4 v = ((const float4*)(flb + t * NN))[i & 15];
            float rt = rn[b * TT + t];
            xns[t][c0] = v.x * rt; xns[t][c0 + 1] = v.y * rt;
            xns[t][c0 + 2] = v.z * rt; xns[t][c0 + 3] = v.w * rt;
        }
    }
    const int r = tid >> 2;
    const int h0 = (tid & 3) * 8;
    const float di = dinv[b * NN + j0 + r];
    const float* zrow = z_in + ((size_t)b * NN + j0 + r) * HH + h0;
    float4 zv0 = ((const float4*)zrow)[0];
    float4 zv1 = ((const float4*)zrow)[1];
    __syncthreads();

    float zreg[8] = { zv0.x, zv0.y, zv0.z, zv0.w, zv1.x, zv1.y, zv1.z, zv1.w };
    // B-phase: next-layer input row chunk -> xs
#pragma unroll
    for (int hh = 0; hh < 8; ++hh) {
        int h = h0 + hh;
        float acc = 0.f;
#pragma unroll
        for (int t = 0; t < TT; ++t) acc += xns[t][r] * us[t][h];
        xs[r][h] = fmaxf(di * (acc + zreg[hh]) + bs[h], 0.f);
    }
    // A-phase: threads 4r..4r+3 (same wave64) wrote xs[r][0..31]; same-wave LDS
    // program-order visibility (validated R1/R2)
    float zr[8];
#pragma unroll
    for (int hh = 0; hh < 8; ++hh) {
        float acc = 0.f;
#pragma unroll
        for (int e = 0; e < 32; ++e) acc += xs[r][e] * Ws[e][h0 + hh];
        zr[hh] = di * acc;
        zs[r][h0 + hh] = zr[hh];
    }
    float* zb = z_out + ((size_t)b * NN + j0 + r) * HH + h0;
    ((float4*)zb)[0] = make_float4(zr[0], zr[1], zr[2], zr[3]);
    ((float4*)zb)[1] = make_float4(zr[4], zr[5], zr[6], zr[7]);
    __syncthreads();

#pragma unroll
    for (int k = 0; k < 3; ++k) {
        int p = tid + k * 256;
        int t = p >> 5, h = p & 31;
        float acc = 0.f;
#pragma unroll 8
        for (int rr = 0; rr < JT; ++rr) acc += xns[t][rr] * zs[rr][h];
        atomicAdd(&u_out[(b * TT + t) * HH + h], acc);
    }
}

// ---------------- K5: final B -> out ----------------
__global__ __launch_bounds__(256) void k_Bfin(const float* __restrict__ z_in,
                                              const float* __restrict__ Flow,
                                              const float* __restrict__ rn,
                                              const float* __restrict__ u_in,
                                              const float* __restrict__ dinv,
                                              const float* __restrict__ bias,
                                              float* __restrict__ out) {
    const int blk = blockIdx.x;
    const int b = blk >> 6;
    const int j0 = (blk & 63) * JT;
    const int tid = threadIdx.x;

    __shared__ float us[TT][32];
    __shared__ float xns[TT][JT];
    __shared__ float bs[32];

    if (tid < 32) bs[tid] = bias[tid];
    if (tid < UPB / 4) {
        float4 v = ((const float4*)(u_in + b * UPB))[tid];
        int t = tid >> 3, c0 = (tid & 7) * 4;
        us[t][c0] = v.x; us[t][c0 + 1] = v.y; us[t][c0 + 2] = v.z; us[t][c0 + 3] = v.w;
    }
    {
        const float* flb = Flow + (size_t)b * TT * NN + j0;
        for (int i = tid; i < TT * (JT / 4); i += 256) {
            int t = i >> 4, c0 = (i & 15) * 4;
            float4 v = ((const float4*)(flb + t * NN))[i & 15];
            float rt = rn[b * TT + t];
            xns[t][c0] = v.x * rt; xns[t][c0 + 1] = v.y * rt;
            xns[t][c0 + 2] = v.z * rt; xns[t][c0 + 3] = v.w * rt;
        }
    }
    const int r = tid >> 2;
    const int h0 = (tid & 3) * 8;
    const float di = dinv[b * NN + j0 + r];
    const float* zrow = z_in + ((size_t)b * NN + j0 + r) * HH + h0;
    float4 zv0 = ((const float4*)zrow)[0];
    float4 zv1 = ((const float4*)zrow)[1];
    __syncthreads();

    float zreg[8] = { zv0.x, zv0.y, zv0.z, zv0.w, zv1.x, zv1.y, zv1.z, zv1.w };
    float o[8];
#pragma unroll
    for (int hh = 0; hh < 8; ++hh) {
        int h = h0 + hh;
        float acc = 0.f;
#pragma unroll
        for (int t = 0; t < TT; ++t) acc += xns[t][r] * us[t][h];
        o[hh] = fmaxf(di * (acc + zreg[hh]) + bs[h], 0.f);
    }
    float* orow = out + ((size_t)b * NN + j0 + r) * HH + h0;
    ((float4*)orow)[0] = make_float4(o[0], o[1], o[2], o[3]);
    ((float4*)orow)[1] = make_float4(o[4], o[5], o[6], o[7]);
}

extern "C" void kernel_launch(void* const* d_in, const int* in_sizes, int n_in,
                              void* d_out, int out_size, void* d_ws, size_t ws_size,
                              hipStream_t stream) {
    const float* Flow = (const float*)d_in[0];
    const float* Edge = (const float*)d_in[1];
    const float* W0 = (const float*)d_in[2];
    const float* b0 = (const float*)d_in[3];
    const float* W1 = (const float*)d_in[4];
    const float* b1 = (const float*)d_in[5];
    const float* W2 = (const float*)d_in[6];
    const float* b2 = (const float*)d_in[7];
    float* out = (float*)d_out;

    float* ws = (float*)d_ws;
    float* rn   = ws;                                   // B*T
    float* s    = rn + BB * TT;                         // B*T
    float* dinv = s + BB * TT;                          // B*N
    float* zA   = dinv + (size_t)BB * NN;               // B*N*H
    float* zB   = zA + (size_t)BB * NN * HH;            // B*N*H
    float* u    = zB + (size_t)BB * NN * HH;            // 3*B*T*H
    float* u0 = u, *u1 = u + BB * TT * HH, *u2 = u + 2 * BB * TT * HH;

    k_norm<<<dim3(BB * TT), 256, 0, stream>>>(Flow, rn, s, u);
    k_dinvA0<<<dim3(512), 256, 0, stream>>>(Flow, Edge, W0, rn, s, dinv, zA, u0);
    k_BA<<<dim3(512), 256, 0, stream>>>(zA, Flow, rn, u0, dinv, b0, W1, zB, u1);
    k_BA<<<dim3(512), 256, 0, stream>>>(zB, Flow, rn, u1, dinv, b1, W2, zA, u2);
    k_Bfin<<<dim3(512), 256, 0, stream>>>(zA, Flow, rn, u2, dinv, b2, out);
}

// Round 6
// 43.065 us; speedup vs baseline: 3.8469x; 1.0761x over previous
//
#include <hip/hip_runtime.h>

#define BB 8
#define TT 24
#define NN 4096   // C*C
#define HH 32
#define JT 64     // j-tile width
#define UPB (TT*HH) // 768

// ---------------- K1: norm (192 blocks) + z0raw = Edge@W0 (512 blocks) ----------------
__global__ __launch_bounds__(256) void k_phase1(const float* __restrict__ Flow,
                                                const float* __restrict__ Edge,
                                                const float* __restrict__ W0,
                                                float* __restrict__ rn,
                                                float* __restrict__ s,
                                                float* __restrict__ u /*3*B*T*H*/,
                                                float* __restrict__ z0raw) {
    const int blk = blockIdx.x;
    const int tid = threadIdx.x;

    if (blk < BB * TT) {
        // ---- norm block: one Flow row ----
        const float4* x = (const float4*)(Flow + (size_t)blk * NN);
        float sq = 0.f, sm = 0.f;
#pragma unroll
        for (int i = 0; i < 4; ++i) {
            float4 v = x[tid + i * 256];
            sq += v.x * v.x + v.y * v.y + v.z * v.z + v.w * v.w;
            sm += v.x + v.y + v.z + v.w;
        }
#pragma unroll
        for (int off = 32; off > 0; off >>= 1) {
            sq += __shfl_down(sq, off);
            sm += __shfl_down(sm, off);
        }
        __shared__ float rss[4], rsm[4];
        int wave = tid >> 6, lane = tid & 63;
        if (lane == 0) { rss[wave] = sq; rsm[wave] = sm; }
        __syncthreads();
        if (tid == 0) {
            float tss = rss[0] + rss[1] + rss[2] + rss[3];
            float tsm = rsm[0] + rsm[1] + rsm[2] + rsm[3];
            float r = 1.0f / fmaxf(sqrtf(tss), 1e-12f);
            rn[blk] = r;
            s[blk] = tsm * r;
        }
        int gid = blk * 256 + tid;
        if (gid < 3 * BB * TT * HH) u[gid] = 0.f;
    } else {
        // ---- GEMM block: z0raw tile = Edge_tile @ W0 ----
        const int g = blk - BB * TT;
        const int b = g >> 6;
        const int j0 = (g & 63) * JT;

        __shared__ float xs[JT][33];
        __shared__ float Ws[32][32];
        for (int i = tid; i < 1024; i += 256) Ws[i >> 5][i & 31] = W0[i];
        {
            const float4* eb = (const float4*)(Edge + ((size_t)b * NN + j0) * HH);
#pragma unroll
            for (int k = 0; k < 2; ++k) {
                int i = tid + k * 256;
                float4 v = eb[i];
                int r0 = i >> 3, c0 = (i & 7) * 4;
                xs[r0][c0] = v.x; xs[r0][c0 + 1] = v.y; xs[r0][c0 + 2] = v.z; xs[r0][c0 + 3] = v.w;
            }
        }
        __syncthreads();
        const int r = tid >> 2;
        const int h0 = (tid & 3) * 8;
        float zr[8];
#pragma unroll
        for (int hh = 0; hh < 8; ++hh) {
            float acc = 0.f;
#pragma unroll
            for (int e = 0; e < 32; ++e) acc += xs[r][e] * Ws[e][h0 + hh];
            zr[hh] = acc;
        }
        float* zb = z0raw + ((size_t)b * NN + j0 + r) * HH + h0;
        ((float4*)zb)[0] = make_float4(zr[0], zr[1], zr[2], zr[3]);
        ((float4*)zb)[1] = make_float4(zr[4], zr[5], zr[6], zr[7]);
    }
}

// ---------------- K2: dinv + u0 partials (no z write) ----------------
__global__ __launch_bounds__(256) void k_dinvU0(const float* __restrict__ Flow,
                                                const float* __restrict__ rn,
                                                const float* __restrict__ s,
                                                const float* __restrict__ z0raw,
                                                float* __restrict__ dinv,
                                                float* __restrict__ u0) {
    const int blk = blockIdx.x;
    const int b = blk >> 6;
    const int j0 = (blk & 63) * JT;
    const int tid = threadIdx.x;

    __shared__ float xns[TT][JT];
    __shared__ float zs[JT][33];
    __shared__ float sS[TT];

    if (tid < TT) sS[tid] = s[b * TT + tid];
    // z0raw tile -> zs (unscaled for now)
    {
        const float4* zt = (const float4*)(z0raw + ((size_t)b * NN + j0) * HH);
#pragma unroll
        for (int k = 0; k < 2; ++k) {
            int i = tid + k * 256;
            float4 v = zt[i];
            int r0 = i >> 3, c0 = (i & 7) * 4;
            zs[r0][c0] = v.x; zs[r0][c0 + 1] = v.y; zs[r0][c0 + 2] = v.z; zs[r0][c0 + 3] = v.w;
        }
    }
    // xn tile
    {
        const float* flb = Flow + (size_t)b * TT * NN + j0;
        for (int i = tid; i < TT * (JT / 4); i += 256) {
            int t = i >> 4, c0 = (i & 15) * 4;
            float4 v = ((const float4*)(flb + t * NN))[i & 15];
            float rt = rn[b * TT + t];
            xns[t][c0] = v.x * rt; xns[t][c0 + 1] = v.y * rt;
            xns[t][c0 + 2] = v.z * rt; xns[t][c0 + 3] = v.w * rt;
        }
    }
    __syncthreads();

    const int r = tid >> 2;
    const int h0 = (tid & 3) * 8;
    float deg = 1.0f;
#pragma unroll
    for (int t = 0; t < TT; ++t) deg += xns[t][r] * sS[t];
    const float di = (deg > 0.f) ? rsqrtf(deg) : 0.f;
    if ((tid & 3) == 0) dinv[b * NN + j0 + r] = di;
    // scale own slice: zs[r][h0..h0+7] *= di
#pragma unroll
    for (int hh = 0; hh < 8; ++hh) zs[r][h0 + hh] *= di;
    __syncthreads();

#pragma unroll
    for (int k = 0; k < 3; ++k) {
        int p = tid + k * 256;
        int t = p >> 5, h = p & 31;
        float acc = 0.f;
#pragma unroll 8
        for (int rr = 0; rr < JT; ++rr) acc += xns[t][rr] * zs[rr][h];
        atomicAdd(&u0[(b * TT + t) * HH + h], acc);
    }
}

// ---------------- K3/K4: fused B(l)+A(l+1), raw-z in/out ----------------
__global__ __launch_bounds__(256) void k_BA(const float* __restrict__ zraw_in,
                                            const float* __restrict__ Flow,
                                            const float* __restrict__ rn,
                                            const float* __restrict__ u_in,
                                            const float* __restrict__ dinv,
                                            const float* __restrict__ bias,
                                            const float* __restrict__ W,
                                            float* __restrict__ zraw_out,
                                            float* __restrict__ u_out) {
    const int blk = blockIdx.x;
    const int b = blk >> 6;
    const int j0 = (blk & 63) * JT;
    const int tid = threadIdx.x;

    __shared__ float us[TT][32];
    __shared__ float xns[TT][JT];
    __shared__ float Ws[32][32];
    __shared__ float xs[JT][33];
    __shared__ float zs[JT][33];
    __shared__ float bs[32];

    if (tid < 32) bs[tid] = bias[tid];
    for (int i = tid; i < 1024; i += 256) Ws[i >> 5][i & 31] = W[i];
    if (tid < UPB / 4) {
        float4 v = ((const float4*)(u_in + b * UPB))[tid];
        int t = tid >> 3, c0 = (tid & 7) * 4;
        us[t][c0] = v.x; us[t][c0 + 1] = v.y; us[t][c0 + 2] = v.z; us[t][c0 + 3] = v.w;
    }
    {
        const float4* zt = (const float4*)(zraw_in + ((size_t)b * NN + j0) * HH);
#pragma unroll
        for (int k = 0; k < 2; ++k) {
            int i = tid + k * 256;
            float4 v = zt[i];
            int r0 = i >> 3, c0 = (i & 7) * 4;
            zs[r0][c0] = v.x; zs[r0][c0 + 1] = v.y; zs[r0][c0 + 2] = v.z; zs[r0][c0 + 3] = v.w;
        }
    }
    {
        const float* flb = Flow + (size_t)b * TT * NN + j0;
        for (int i = tid; i < TT * (JT / 4); i += 256) {
            int t = i >> 4, c0 = (i & 15) * 4;
            float4 v = ((const float4*)(flb + t * NN))[i & 15];
            float rt = rn[b * TT + t];
            xns[t][c0] = v.x * rt; xns[t][c0 + 1] = v.y * rt;
            xns[t][c0 + 2] = v.z * rt; xns[t][c0 + 3] = v.w * rt;
        }
    }
    const int r = tid >> 2;
    const int h0 = (tid & 3) * 8;
    const float di = dinv[b * NN + j0 + r];
    __syncthreads();

    // z_in scaled into registers
    float zreg[8];
#pragma unroll
    for (int hh = 0; hh < 8; ++hh) zreg[hh] = di * zs[r][h0 + hh];
    // B-phase: next-layer input row chunk -> xs
#pragma unroll
    for (int hh = 0; hh < 8; ++hh) {
        int h = h0 + hh;
        float acc = 0.f;
#pragma unroll
        for (int t = 0; t < TT; ++t) acc += xns[t][r] * us[t][h];
        xs[r][h] = fmaxf(di * (acc + zreg[hh]) + bs[h], 0.f);
    }
    // A-phase: threads 4r..4r+3 (same wave64) wrote xs[r][0..31]; same-wave LDS
    // program-order visibility (validated R1/R2/R4)
    float zr[8];
#pragma unroll
    for (int hh = 0; hh < 8; ++hh) {
        float acc = 0.f;
#pragma unroll
        for (int e = 0; e < 32; ++e) acc += xs[r][e] * Ws[e][h0 + hh];
        zr[hh] = acc;                    // raw
        zs[r][h0 + hh] = di * zr[hh];    // scaled, for u partial (own slice only)
    }
    float* zb = zraw_out + ((size_t)b * NN + j0 + r) * HH + h0;
    ((float4*)zb)[0] = make_float4(zr[0], zr[1], zr[2], zr[3]);
    ((float4*)zb)[1] = make_float4(zr[4], zr[5], zr[6], zr[7]);
    __syncthreads();

#pragma unroll
    for (int k = 0; k < 3; ++k) {
        int p = tid + k * 256;
        int t = p >> 5, h = p & 31;
        float acc = 0.f;
#pragma unroll 8
        for (int rr = 0; rr < JT; ++rr) acc += xns[t][rr] * zs[rr][h];
        atomicAdd(&u_out[(b * TT + t) * HH + h], acc);
    }
}

// ---------------- K5: final B -> out ----------------
__global__ __launch_bounds__(256) void k_Bfin(const float* __restrict__ zraw_in,
                                              const float* __restrict__ Flow,
                                              const float* __restrict__ rn,
                                              const float* __restrict__ u_in,
                                              const float* __restrict__ dinv,
                                              const float* __restrict__ bias,
                                              float* __restrict__ out) {
    const int blk = blockIdx.x;
    const int b = blk >> 6;
    const int j0 = (blk & 63) * JT;
    const int tid = threadIdx.x;

    __shared__ float us[TT][32];
    __shared__ float xns[TT][JT];
    __shared__ float bs[32];

    if (tid < 32) bs[tid] = bias[tid];
    if (tid < UPB / 4) {
        float4 v = ((const float4*)(u_in + b * UPB))[tid];
        int t = tid >> 3, c0 = (tid & 7) * 4;
        us[t][c0] = v.x; us[t][c0 + 1] = v.y; us[t][c0 + 2] = v.z; us[t][c0 + 3] = v.w;
    }
    {
        const float* flb = Flow + (size_t)b * TT * NN + j0;
        for (int i = tid; i < TT * (JT / 4); i += 256) {
            int t = i >> 4, c0 = (i & 15) * 4;
            float4 v = ((const float4*)(flb + t * NN))[i & 15];
            float rt = rn[b * TT + t];
            xns[t][c0] = v.x * rt; xns[t][c0 + 1] = v.y * rt;
            xns[t][c0 + 2] = v.z * rt; xns[t][c0 + 3] = v.w * rt;
        }
    }
    const int r = tid >> 2;
    const int h0 = (tid & 3) * 8;
    const float di = dinv[b * NN + j0 + r];
    const float* zrow = zraw_in + ((size_t)b * NN + j0 + r) * HH + h0;
    float4 zv0 = ((const float4*)zrow)[0];
    float4 zv1 = ((const float4*)zrow)[1];
    __syncthreads();

    float zreg[8] = { di * zv0.x, di * zv0.y, di * zv0.z, di * zv0.w,
                      di * zv1.x, di * zv1.y, di * zv1.z, di * zv1.w };
    float o[8];
#pragma unroll
    for (int hh = 0; hh < 8; ++hh) {
        int h = h0 + hh;
        float acc = 0.f;
#pragma unroll
        for (int t = 0; t < TT; ++t) acc += xns[t][r] * us[t][h];
        o[hh] = fmaxf(di * (acc + zreg[hh]) + bs[h], 0.f);
    }
    float* orow = out + ((size_t)b * NN + j0 + r) * HH + h0;
    ((float4*)orow)[0] = make_float4(o[0], o[1], o[2], o[3]);
    ((float4*)orow)[1] = make_float4(o[4], o[5], o[6], o[7]);
}

extern "C" void kernel_launch(void* const* d_in, const int* in_sizes, int n_in,
                              void* d_out, int out_size, void* d_ws, size_t ws_size,
                              hipStream_t stream) {
    const float* Flow = (const float*)d_in[0];
    const float* Edge = (const float*)d_in[1];
    const float* W0 = (const float*)d_in[2];
    const float* b0 = (const float*)d_in[3];
    const float* W1 = (const float*)d_in[4];
    const float* b1 = (const float*)d_in[5];
    const float* W2 = (const float*)d_in[6];
    const float* b2 = (const float*)d_in[7];
    float* out = (float*)d_out;

    float* ws = (float*)d_ws;
    float* rn   = ws;                                   // B*T
    float* s    = rn + BB * TT;                         // B*T
    float* dinv = s + BB * TT;                          // B*N
    float* zA   = dinv + (size_t)BB * NN;               // B*N*H (raw)
    float* zB   = zA + (size_t)BB * NN * HH;            // B*N*H (raw)
    float* u    = zB + (size_t)BB * NN * HH;            // 3*B*T*H
    float* u0 = u, *u1 = u + BB * TT * HH, *u2 = u + 2 * BB * TT * HH;

    k_phase1<<<dim3(BB * TT + 512), 256, 0, stream>>>(Flow, Edge, W0, rn, s, u, zA);
    k_dinvU0<<<dim3(512), 256, 0, stream>>>(Flow, rn, s, zA, dinv, u0);
    k_BA<<<dim3(512), 256, 0, stream>>>(zA, Flow, rn, u0, dinv, b0, W1, zB, u1);
    k_BA<<<dim3(512), 256, 0, stream>>>(zB, Flow, rn, u1, dinv, b1, W2, zA, u2);
    k_Bfin<<<dim3(512), 256, 0, stream>>>(zA, Flow, rn, u2, dinv, b2, out);
}